// Round 12
// baseline (201.684 us; speedup 1.0000x reference)
//
#include <hip/hip_runtime.h>
#include <hip/hip_bf16.h>
#include <cmath>

typedef _Float16 half_t;
typedef half_t half4 __attribute__((ext_vector_type(4)));
typedef half_t half8 __attribute__((ext_vector_type(8)));
typedef float f32x4 __attribute__((ext_vector_type(4)));

#define N_HEADS 16
#define HD      64
#define T_SEQ   2048
#define B_SZ    2
#define C_DIM   1024
#define M_ROWS  (B_SZ * T_SEQ)   /* 4096 */
#define N_QKV   (3 * C_DIM)      /* 3072 */
#define QSCALE  0.18033688f      /* 0.125 * log2(e), folded into Q at rope */

__device__ inline void load_lds16(const half_t* g, half_t* l) {
  __builtin_amdgcn_global_load_lds(
      (const __attribute__((address_space(1))) void*)g,
      (__attribute__((address_space(3))) void*)l, 16, 0, 0);
}

// ---- fused prep: x->f16 (0..4095), w_attn^T (..4863), w_proj^T (..5119),
// ---- rope cos/sin table (5120..5375): tbl[t][j] = {cos,sin}(t*10000^(-j/32))
__global__ __launch_bounds__(256) void k_prep(const float* __restrict__ x,
                                              half_t* __restrict__ xb,
                                              const float* __restrict__ wa,
                                              half_t* __restrict__ wT,
                                              const float* __restrict__ wp,
                                              half_t* __restrict__ wpT,
                                              float2* __restrict__ tbl) {
  __shared__ float tile[64][65];
  int bid = blockIdx.x, tid = threadIdx.x;
  if (bid < 4096) {
    int i = (bid * 256 + tid) * 4;
    float4 v = *(const float4*)(x + i);
    half_t o[4] = {(half_t)v.x, (half_t)v.y, (half_t)v.z, (half_t)v.w};
    *(ulong1*)(xb + i) = *(ulong1*)o;
    return;
  }
  if (bid >= 5120) {                       // rope table: 65536 entries
    int idx = (bid - 5120) * 256 + tid;
    int t = idx >> 5, j = idx & 31;
    float inv = exp2f(-(float)j * (13.287712379549449f / 32.0f));
    float s, c;
    sincosf((float)t * inv, &s, &c);
    tbl[idx] = make_float2(c, s);
    return;
  }
  const float* in; half_t* out; int K, N, id;
  if (bid < 4864) { id = bid - 4096; in = wa; out = wT;  K = 1024; N = 3072; }
  else            { id = bid - 4864; in = wp; out = wpT; K = 1024; N = 1024; }
  int n0 = (id % (N / 64)) * 64, k0 = (id / (N / 64)) * 64;
  int tx = tid & 63, ty = tid >> 6;
  #pragma unroll
  for (int i = 0; i < 64; i += 4)
    tile[ty + i][tx] = in[(size_t)(k0 + ty + i) * N + n0 + tx];
  __syncthreads();
  #pragma unroll
  for (int i = 0; i < 64; i += 4) {
    int r = ty + i;
    out[(size_t)(n0 + r) * K + k0 + tx] = (half_t)tile[tx][r];
  }
}

// ------------- GEMM: C = A(f16,[M][K]) * Bt(f16,[N][K])^T + bias, OT out ----
// 128xTN tile, BK=64, double-buffered prefetch (one barrier per K-iter).
template <typename OT, int TN>
__global__ __launch_bounds__(256) void k_gemm(const half_t* __restrict__ A,
                                              const half_t* __restrict__ Bt,
                                              const float* __restrict__ bias,
                                              OT* __restrict__ C,
                                              int M, int N, int K) {
  constexpr int NI = TN / 32;          // n-fragments per wave
  __shared__ half_t As[2][128 * 64];
  __shared__ half_t Bs[2][TN * 64];
  int tid = threadIdx.x;
  int wave = tid >> 6, lane = tid & 63;
  int lane15 = lane & 15, quad = lane >> 4;
  int wm = (wave >> 1) * 64, wn = (wave & 1) * (TN / 2);
  int bm0 = blockIdx.y * 128, bn0 = blockIdx.x * TN;
  f32x4 acc[4][NI] = {};

#define G_STAGE(bb, kb)                                                        \
  {                                                                            \
    const half_t* Ag = A + (size_t)bm0 * K + (kb);                             \
    const half_t* Bg = Bt + (size_t)bn0 * K + (kb);                            \
    _Pragma("unroll")                                                          \
    for (int p = 0; p < 4; p++) {                                              \
      int fc = wave * 4 * 64 + p * 64 + lane;                                  \
      int r = fc >> 3, c = (fc & 7) ^ (r & 7);                                 \
      load_lds16(Ag + (size_t)r * K + c * 8, &As[bb][0] + (wave * 4 + p) * 512); \
    }                                                                          \
    _Pragma("unroll")                                                          \
    for (int p = 0; p < NI; p++) {                                             \
      int fc = wave * NI * 64 + p * 64 + lane;                                 \
      int r = fc >> 3, c = (fc & 7) ^ (r & 7);                                 \
      load_lds16(Bg + (size_t)r * K + c * 8, &Bs[bb][0] + (wave * NI + p) * 512); \
    }                                                                          \
  }

  G_STAGE(0, 0);
  int NT = K / 64;
  for (int kt = 0; kt < NT; kt++) {
    __syncthreads();                       // buf[kt&1] DMA drained & visible
    if (kt + 1 < NT) G_STAGE((kt + 1) & 1, (kt + 1) * 64);
    const half_t* Asb = &As[kt & 1][0];
    const half_t* Bsb = &Bs[kt & 1][0];
    #pragma unroll
    for (int ks = 0; ks < 2; ks++) {
      half8 af[4], bf[NI];
      #pragma unroll
      for (int i = 0; i < 4; i++) {
        int Ra = wm + i * 16 + lane15;
        af[i] = *(const half8*)(Asb + Ra * 64 + ((ks * 4 + quad) ^ (Ra & 7)) * 8);
      }
      #pragma unroll
      for (int i = 0; i < NI; i++) {
        int Rb = wn + i * 16 + lane15;
        bf[i] = *(const half8*)(Bsb + Rb * 64 + ((ks * 4 + quad) ^ (Rb & 7)) * 8);
      }
      #pragma unroll
      for (int mi = 0; mi < 4; mi++)
        #pragma unroll
        for (int ni = 0; ni < NI; ni++)
          acc[mi][ni] = __builtin_amdgcn_mfma_f32_16x16x32_f16(af[mi], bf[ni], acc[mi][ni], 0, 0, 0);
    }
  }
#undef G_STAGE
  #pragma unroll
  for (int mi = 0; mi < 4; mi++)
    #pragma unroll
    for (int ni = 0; ni < NI; ni++) {
      int n = bn0 + wn + ni * 16 + lane15;
      float bv = bias[n];
      int mrow = bm0 + wm + mi * 16 + quad * 4;
      #pragma unroll
      for (int r = 0; r < 4; r++)
        C[(size_t)(mrow + r) * N + n] = (OT)(acc[mi][ni][r] + bv);
    }
}

// ------------- fused QKV GEMM + bias + RoPE + reorg (v3: 512 threads) -------------
// R11 win: 512 thr / 8 waves (4Mx2N), acc 64->32 AGPR -> 2 blocks/CU.
__global__ __launch_bounds__(512, 4) void k_gemm_qkv(const half_t* __restrict__ A,
                                                     const half_t* __restrict__ Bt,
                                                     const float* __restrict__ bias,
                                                     const float2* __restrict__ tbl,
                                                     half_t* __restrict__ Qo,
                                                     half_t* __restrict__ Ko,
                                                     half_t* __restrict__ Vo) {
  __shared__ half_t smem[2][16384];        // per buf: As 8192h | Bs 8192h (64KB)
  int tid = threadIdx.x;
  int wave = tid >> 6, lane = tid & 63;
  int lane15 = lane & 15, quad = lane >> 4;
  int wm = (wave >> 1) * 32, wn = (wave & 1) * 64;   // 4M x 2N wave grid
  int bm0 = blockIdx.y * 128, bn0 = blockIdx.x * 128;
  f32x4 acc[2][4] = {};                    // [mi][ni]: 32 AGPR

#define QKV_STAGE(bb, kb)                                                      \
  {                                                                            \
    const half_t* Ag = A + (size_t)bm0 * C_DIM + (kb);                         \
    const half_t* Bg = Bt + (size_t)bn0 * C_DIM + (kb);                        \
    _Pragma("unroll")                                                          \
    for (int p = 0; p < 2; p++) {                                              \
      int fc = (wave * 2 + p) * 64 + lane;                                     \
      int r = fc >> 3, c = (fc & 7) ^ (r & 7);                                 \
      load_lds16(Ag + (size_t)r * C_DIM + c * 8,                               \
                 &smem[bb][0] + (wave * 2 + p) * 512);                         \
      load_lds16(Bg + (size_t)r * C_DIM + c * 8,                               \
                 &smem[bb][8192] + (wave * 2 + p) * 512);                      \
    }                                                                          \
  }

  QKV_STAGE(0, 0);
  for (int kt = 0; kt < 16; kt++) {
    __syncthreads();                       // buf[kt&1] DMA drained & visible
    if (kt < 15) QKV_STAGE((kt + 1) & 1, (kt + 1) * 64);
    const half_t* As = &smem[kt & 1][0];
    const half_t* Bs = &smem[kt & 1][8192];
    #pragma unroll
    for (int ks = 0; ks < 2; ks++) {
      half8 af[2], bf[4];
      #pragma unroll
      for (int i = 0; i < 2; i++) {
        int Ra = wm + i * 16 + lane15;
        af[i] = *(const half8*)(As + Ra * 64 + ((ks * 4 + quad) ^ (Ra & 7)) * 8);
      }
      #pragma unroll
      for (int i = 0; i < 4; i++) {
        int Rb = wn + i * 16 + lane15;
        bf[i] = *(const half8*)(Bs + Rb * 64 + ((ks * 4 + quad) ^ (Rb & 7)) * 8);
      }
      #pragma unroll
      for (int mi = 0; mi < 2; mi++)
        #pragma unroll
        for (int ni = 0; ni < 4; ni++)
          acc[mi][ni] = __builtin_amdgcn_mfma_f32_16x16x32_f16(af[mi], bf[ni], acc[mi][ni], 0, 0, 0);
    }
  }
#undef QKV_STAGE
  // bias (b_attn) BEFORE rope, matching reference
  #pragma unroll
  for (int ni = 0; ni < 4; ni++) {
    float bv = bias[bn0 + wn + ni * 16 + lane15];
    #pragma unroll
    for (int mi = 0; mi < 2; mi++)
      #pragma unroll
      for (int r = 0; r < 4; r++) acc[mi][ni][r] += bv;
  }

  int third = bn0 >> 10;                   // 0=Q, 1=K, 2=V (block-uniform)
  if (third < 2) {
    half_t* Ob = (third == 0) ? Qo : Ko;
    int h = ((bn0 & 1023) + wn) >> 6;      // one head per wave (wn in {0,64})
    #pragma unroll
    for (int mi = 0; mi < 2; mi++) {
      int mrow = bm0 + wm + mi * 16 + quad * 4;
      int bq = mrow >> 11, tq = mrow & 2047;
      half_t* outp = Ob + ((size_t)(bq * 16 + h) * T_SEQ + tq) * HD;
      #pragma unroll
      for (int p = 0; p < 2; p++) {        // pair (d=j, d=j+32), j = p*16+lane15
        int j = p * 16 + lane15;
        #pragma unroll
        for (int r = 0; r < 4; r++) {
          float2 cs = tbl[(tq + r) * 32 + j];
          float a1 = acc[mi][p][r], a2 = acc[mi][p + 2][r];
          float o1 = a1 * cs.x - a2 * cs.y;
          float o2 = a1 * cs.y + a2 * cs.x;
          if (third == 0) { o1 *= QSCALE; o2 *= QSCALE; }
          outp[r * HD + j]      = (half_t)o1;
          outp[r * HD + j + 32] = (half_t)o2;
        }
      }
    }
  } else {
    // V: transpose through LDS, store blocked [bh][t/64][d][t%64]
    __syncthreads();                       // all waves done reading smem
    half_t* vt = &smem[0][0];              // [128][130], 33280B < 64KB
    #pragma unroll
    for (int mi = 0; mi < 2; mi++)
      #pragma unroll
      for (int ni = 0; ni < 4; ni++) {
        int tl = wm + mi * 16 + quad * 4, nl = wn + ni * 16 + lane15;
        #pragma unroll
        for (int r = 0; r < 4; r++)
          vt[(tl + r) * 130 + nl] = (half_t)acc[mi][ni][r];
      }
    __syncthreads();
    int hV = (bn0 - 2048) >> 6;
    int bq = bm0 >> 11, tq0 = bm0 & 2047;
    int c8 = (tid & 7) * 8;                // 8 lanes cover one 64-t row chunk
    #pragma unroll
    for (int p = 0; p < 4; p++) {
      int gr = p * 64 + (tid >> 3);        // 256 rows: (h2, d, tblk)
      int tb = gr & 1, d = (gr >> 1) & 63, h2 = gr >> 7;
      half8 vv;
      #pragma unroll
      for (int jj = 0; jj < 8; jj++)
        vv[jj] = vt[(tb * 64 + c8 + jj) * 130 + h2 * 64 + d];
      *(half8*)(Vo + ((size_t)((bq * 16 + hV + h2) * 32 + (tq0 >> 6) + tb) * 64 + d) * 64 + c8) = vv;
    }
  }
}

// ------------- causal flash v6: l-via-MFMA + setprio -------------
// R11 correction: flash pinned at ~45us across v3/v4/v5 (kv-split, XCD swizzle,
// barrier halving all null on duration). Counters: VALUBusy 51 vs MfmaUtil 22
// -> VALU-issue-bound with serial QK->softmax->PV phases. v6 moves the
// l-accumulation (16 VALU adds/tile + 2 end shuffles) onto the idle MFMA pipe:
// ot_l = mfma_16x16x16(ones, bp, ot_l) gives Sum_kv P[kv][q] exactly (A=ones),
// masked scores contribute exp2(-1e30)=0. All 4 acc rows identical -> read [0];
// cross-quad sum is internal to the MFMA (K=16 spans all quads) -> shfls gone.
// T5 setprio(1) around PV MFMA clusters (waves de-phase via A/B branch paths).
template <bool DIAG>
__device__ __forceinline__ void tile_mfma(const half_t* __restrict__ Kt,
                                          const half_t* __restrict__ Vt,
                                          half8 bq0, half8 bq1,
                                          f32x4 (&ot)[4], f32x4& ot_l,
                                          int lane15, int quad, int qloc) {
  const half4 ones = {(half_t)1.f, (half_t)1.f, (half_t)1.f, (half_t)1.f};
  f32x4 sacc[4];
  #pragma unroll
  for (int s = 0; s < 4; s++) {
    int R_ = s * 16 + lane15;
    half8 ak0 = *(const half8*)(Kt + R_ * 64 + ((quad) ^ (R_ & 7)) * 8);
    half8 ak1 = *(const half8*)(Kt + R_ * 64 + ((4 + quad) ^ (R_ & 7)) * 8);
    f32x4 z = {};
    z = __builtin_amdgcn_mfma_f32_16x16x32_f16(ak0, bq0, z, 0, 0, 0);
    sacc[s] = __builtin_amdgcn_mfma_f32_16x16x32_f16(ak1, bq1, z, 0, 0, 0);
  }
  #pragma unroll
  for (int s = 0; s < 4; s++) {
    half4 bp;
    #pragma unroll
    for (int r = 0; r < 4; r++) {
      float sv = sacc[s][r];
      if (DIAG && (s * 16 + quad * 4 + r > qloc)) sv = -1.0e30f;
      bp[r] = (half_t)exp2f(fminf(sv, 14.0f));
    }
    __builtin_amdgcn_s_setprio(1);
    ot_l = __builtin_amdgcn_mfma_f32_16x16x16f16(ones, bp, ot_l, 0, 0, 0);
    #pragma unroll
    for (int nm = 0; nm < 4; nm++) {
      int Rv = nm * 16 + lane15;
      half4 av = *(const half4*)(Vt + Rv * 64 +
                                 ((2 * s + (quad >> 1)) ^ (Rv & 7)) * 8 +
                                 (quad & 1) * 4);
      ot[nm] = __builtin_amdgcn_mfma_f32_16x16x16f16(av, bp, ot[nm], 0, 0, 0);
    }
    __builtin_amdgcn_s_setprio(0);
  }
}

// Stage super-round s_: kv tiles {4s, 4s+1} (sub 0) and {4s+2, 4s+3} (sub 1)
// of K and V into buffer bb. 1024 threads x 4 load_lds16 (16B) = 64KB.
#define STAGE2(bb, s_)                                                         \
  {                                                                            \
    int gS = wave >> 3;                                                        \
    int idx = (wave & 7) * 64 + lane;                                          \
    int rr_ = idx >> 3, cc = (idx & 7) ^ (rr_ & 7);                            \
    _Pragma("unroll")                                                          \
    for (int sub = 0; sub < 2; sub++) {                                        \
      int j = 4 * (s_) + 2 * sub + gS;                                         \
      load_lds16(Kb + (size_t)(j * 64 + rr_) * HD + cc * 8,                    \
                 &KV[bb][sub][0][gS][0] + idx * 8);                            \
      load_lds16(Vb + (size_t)j * 4096 + rr_ * 64 + cc * 8,                    \
                 &KV[bb][sub][1][gS][0] + idx * 8);                            \
    }                                                                          \
  }

__global__ __launch_bounds__(1024, 4) void k_flash(const half_t* __restrict__ Qg,
                                                   const half_t* __restrict__ Kg,
                                                   const half_t* __restrict__ Vg,
                                                   half_t* __restrict__ y) {
  __shared__ half_t KV[2][2][2][2][4096];  // [buf][sub][K/V][parity][64*64] 128KB
  // XCD-colocation swizzle (XCD = flat % 8): all 8 blocks of one bh share an
  // XCD -> K/V L2-resident (verified R8: FETCH 71.5 -> 12.4MB).
  int flat = (int)blockIdx.x + 8 * (int)blockIdx.y;
  int x  = (flat >> 3) & 7;                // q-tile pair id 0..7
  int bh = (flat & 7) | ((flat >> 6) << 3);
  int b = bh >> 4, h = bh & 15;
  int tid = threadIdx.x;
  int wave = tid >> 6, lane = tid & 63;
  int g = wave >> 3, wq = wave & 7;        // kv-parity group, q-warp in group
  int lane15 = lane & 15, quad = lane >> 4;
  const half_t* Qb = Qg + (size_t)bh * T_SEQ * HD;
  const half_t* Kb = Kg + (size_t)bh * T_SEQ * HD;
  const half_t* Vb = Vg + (size_t)bh * HD * T_SEQ;

  int qtA = x, qtB = 15 - x;               // A < B always
  int jA = 2 * qtA, jB = 2 * qtB;          // diagonal kv-tile bases
  int qlA = qtA * 128 + wq * 16 + lane15;
  int qlB = qtB * 128 + wq * 16 + lane15;
  half8 aq0 = *(const half8*)(Qb + (size_t)qlA * HD + quad * 8);
  half8 aq1 = *(const half8*)(Qb + (size_t)qlA * HD + 32 + quad * 8);
  half8 bq0 = *(const half8*)(Qb + (size_t)qlB * HD + quad * 8);
  half8 bq1 = *(const half8*)(Qb + (size_t)qlB * HD + 32 + quad * 8);
  f32x4 otA[4] = {}, otB[4] = {};
  f32x4 otA_l = {}, otB_l = {};

  int R = 16 - x;                          // rounds; tiles consumed 2/round
  int S = (R + 1) >> 1;                    // super-rounds (4 tiles per stage)
  STAGE2(0, 0);
  for (int s = 0; s < S; s++) {
    __syncthreads();                       // stage(s) DMA drained & visible
    if (s + 1 < S) STAGE2((s + 1) & 1, s + 1);  // prefetch overlaps compute
    #pragma unroll
    for (int sub = 0; sub < 2; sub++) {
      const half_t* Kt = &KV[s & 1][sub][0][g][0];
      const half_t* Vt = &KV[s & 1][sub][1][g][0];
      int j = 2 * (2 * s + sub) + g;       // this group's kv tile
      // tile A (q rows 128x..128x+127): active while j <= jA+1
      if (j < jA)
        tile_mfma<false>(Kt, Vt, aq0, aq1, otA, otA_l, lane15, quad, 0);
      else if (j == jA)                    // parity 0 -> group 0 only
        tile_mfma<true>(Kt, Vt, aq0, aq1, otA, otA_l, lane15, quad,
                        wq * 16 + lane15);
      else if (j == jA + 1 && wq >= 4)     // parity 1 -> group 1; wq<4 masked
        tile_mfma<true>(Kt, Vt, aq0, aq1, otA, otA_l, lane15, quad,
                        (wq - 4) * 16 + lane15);
      // tile B (q rows 128(15-x)..): active while j <= jB+1
      if (j < jB)
        tile_mfma<false>(Kt, Vt, bq0, bq1, otB, otB_l, lane15, quad, 0);
      else if (j == jB)
        tile_mfma<true>(Kt, Vt, bq0, bq1, otB, otB_l, lane15, quad,
                        wq * 16 + lane15);
      else if (j == jB + 1 && wq >= 4)
        tile_mfma<true>(Kt, Vt, bq0, bq1, otB, otB_l, lane15, quad,
                        (wq - 4) * 16 + lane15);
    }
  }
  // l is fully reduced inside the ones-MFMA (K=16 spans all quads): rows equal
  float lA = otA_l[0], lB = otB_l[0];
  // cross-group combine via LDS (reuse KV region, 512*17*4B = 34.8KB <= 128KB)
  float* cb = (float*)&KV[0][0][0][0][0];
  int ci = (wq * 64 + lane) * 17;          // stride 17 floats: conflict-free
  // ---- tile A ----
  __syncthreads();                         // all K/V reads done; region free
  if (g == 1) {
    #pragma unroll
    for (int nm = 0; nm < 4; nm++)
      #pragma unroll
      for (int r = 0; r < 4; r++) cb[ci + nm * 4 + r] = otA[nm][r];
    cb[ci + 16] = lA;
  }
  __syncthreads();
  if (g == 0) {
    #pragma unroll
    for (int nm = 0; nm < 4; nm++)
      #pragma unroll
      for (int r = 0; r < 4; r++) otA[nm][r] += cb[ci + nm * 4 + r];
    lA += cb[ci + 16];
    float invl = 1.0f / lA;
    int t = qtA * 128 + wq * 16 + lane15;
    half_t* yr = y + (size_t)(b * T_SEQ + t) * C_DIM + h * 64;
    #pragma unroll
    for (int nm = 0; nm < 4; nm++) {
      half4 o4;
      #pragma unroll
      for (int r = 0; r < 4; r++) o4[r] = (half_t)(otA[nm][r] * invl);
      *(half4*)(yr + nm * 16 + quad * 4) = o4;   // 8B store
    }
  }
  // ---- tile B ----
  __syncthreads();
  if (g == 1) {
    #pragma unroll
    for (int nm = 0; nm < 4; nm++)
      #pragma unroll
      for (int r = 0; r < 4; r++) cb[ci + nm * 4 + r] = otB[nm][r];
    cb[ci + 16] = lB;
  }
  __syncthreads();
  if (g == 0) {
    #pragma unroll
    for (int nm = 0; nm < 4; nm++)
      #pragma unroll
      for (int r = 0; r < 4; r++) otB[nm][r] += cb[ci + nm * 4 + r];
    lB += cb[ci + 16];
    float invl = 1.0f / lB;
    int t = qtB * 128 + wq * 16 + lane15;
    half_t* yr = y + (size_t)(b * T_SEQ + t) * C_DIM + h * 64;
    #pragma unroll
    for (int nm = 0; nm < 4; nm++) {
      half4 o4;
      #pragma unroll
      for (int r = 0; r < 4; r++) o4[r] = (half_t)(otB[nm][r] * invl);
      *(half4*)(yr + nm * 16 + quad * 4) = o4;   // 8B store
    }
  }
  #undef STAGE2
}

extern "C" void kernel_launch(void* const* d_in, const int* in_sizes, int n_in,
                              void* d_out, int out_size, void* d_ws, size_t ws_size,
                              hipStream_t stream) {
  const float* x      = (const float*)d_in[0];
  const float* w_attn = (const float*)d_in[1];
  const float* b_attn = (const float*)d_in[2];
  const float* w_proj = (const float*)d_in[3];
  const float* b_proj = (const float*)d_in[4];
  float* out = (float*)d_out;

  char* ws = (char*)d_ws;
  const size_t MB = 1u << 20;
  half_t* xb  = (half_t*)(ws);             // 8 MB  x in f16
  half_t* wT  = (half_t*)(ws + 8 * MB);    // 6 MB  w_attn^T f16 [3072][1024]
  half_t* wpT = (half_t*)(ws + 14 * MB);   // 2 MB  w_proj^T f16 [1024][1024]
  half_t* Q   = (half_t*)(ws + 16 * MB);   // 8 MB  [bh][t][d]  (pre-scaled)
  half_t* Kb  = (half_t*)(ws + 24 * MB);   // 8 MB  [bh][t][d]
  half_t* Vt  = (half_t*)(ws + 32 * MB);   // 8 MB  [bh][t/64][d][t%64] blocked
  half_t* y   = (half_t*)(ws + 40 * MB);   // 8 MB  attn out f16
  float2* tbl = (float2*)(ws + 48 * MB);   // 512KB rope table [2048][32]

  k_prep<<<4096 + 768 + 256 + 256, 256, 0, stream>>>(x, xb, w_attn, wT,
                                                     w_proj, wpT, tbl);
  k_gemm_qkv<<<dim3(N_QKV / 128, M_ROWS / 128), 512, 0, stream>>>(
      xb, wT, b_attn, tbl, Q, Kb, Vt);
  k_flash<<<dim3(8, B_SZ * N_HEADS), 1024, 0, stream>>>(Q, Kb, Vt, y);
  k_gemm<float, 64><<<dim3(C_DIM / 64, M_ROWS / 128), 256, 0, stream>>>(
      y, wpT, b_proj, out, M_ROWS, C_DIM, C_DIM);
}

// Round 13
// 173.387 us; speedup vs baseline: 1.1632x; 1.1632x over previous
//
#include <hip/hip_runtime.h>
#include <hip/hip_bf16.h>
#include <cmath>

typedef _Float16 half_t;
typedef half_t half4 __attribute__((ext_vector_type(4)));
typedef half_t half8 __attribute__((ext_vector_type(8)));
typedef float f32x4 __attribute__((ext_vector_type(4)));

#define N_HEADS 16
#define HD      64
#define T_SEQ   2048
#define B_SZ    2
#define C_DIM   1024
#define M_ROWS  (B_SZ * T_SEQ)   /* 4096 */
#define N_QKV   (3 * C_DIM)      /* 3072 */
#define QSCALE  0.18033688f      /* 0.125 * log2(e), folded into Q at rope */

__device__ inline void load_lds16(const half_t* g, half_t* l) {
  __builtin_amdgcn_global_load_lds(
      (const __attribute__((address_space(1))) void*)g,
      (__attribute__((address_space(3))) void*)l, 16, 0, 0);
}

// ---- fused prep: x->f16 (0..4095), w_attn^T (..4863), w_proj^T (..5119),
// ---- rope cos/sin table (5120..5375): tbl[t][j] = {cos,sin}(t*10000^(-j/32))
__global__ __launch_bounds__(256) void k_prep(const float* __restrict__ x,
                                              half_t* __restrict__ xb,
                                              const float* __restrict__ wa,
                                              half_t* __restrict__ wT,
                                              const float* __restrict__ wp,
                                              half_t* __restrict__ wpT,
                                              float2* __restrict__ tbl) {
  __shared__ float tile[64][65];
  int bid = blockIdx.x, tid = threadIdx.x;
  if (bid < 4096) {
    int i = (bid * 256 + tid) * 4;
    float4 v = *(const float4*)(x + i);
    half_t o[4] = {(half_t)v.x, (half_t)v.y, (half_t)v.z, (half_t)v.w};
    *(ulong1*)(xb + i) = *(ulong1*)o;
    return;
  }
  if (bid >= 5120) {                       // rope table: 65536 entries
    int idx = (bid - 5120) * 256 + tid;
    int t = idx >> 5, j = idx & 31;
    float inv = exp2f(-(float)j * (13.287712379549449f / 32.0f));
    float s, c;
    sincosf((float)t * inv, &s, &c);
    tbl[idx] = make_float2(c, s);
    return;
  }
  const float* in; half_t* out; int K, N, id;
  if (bid < 4864) { id = bid - 4096; in = wa; out = wT;  K = 1024; N = 3072; }
  else            { id = bid - 4864; in = wp; out = wpT; K = 1024; N = 1024; }
  int n0 = (id % (N / 64)) * 64, k0 = (id / (N / 64)) * 64;
  int tx = tid & 63, ty = tid >> 6;
  #pragma unroll
  for (int i = 0; i < 64; i += 4)
    tile[ty + i][tx] = in[(size_t)(k0 + ty + i) * N + n0 + tx];
  __syncthreads();
  #pragma unroll
  for (int i = 0; i < 64; i += 4) {
    int r = ty + i;
    out[(size_t)(n0 + r) * K + k0 + tx] = (half_t)tile[tx][r];
  }
}

// ------------- gemm2: out = y(f16,[4096][1024]) * wpT(f16,[1024][1024])^T + b ----
// R13: 512 threads / 8 waves (4Mx2N, wave tile 32x32), acc[2][2]=16 AGPR,
// launch_bounds(512,4) -> 2+ blocks/CU (the R11 occupancy transform that took
// gemm_qkv 53 -> <45us). Tile 128x64, BK=64, dbuf prefetch, 48KB LDS.
__global__ __launch_bounds__(512, 4) void k_gemm2(const half_t* __restrict__ A,
                                                  const half_t* __restrict__ Bt,
                                                  const float* __restrict__ bias,
                                                  float* __restrict__ C) {
  __shared__ half_t As[2][128 * 64];
  __shared__ half_t Bs[2][64 * 64];
  int tid = threadIdx.x;
  int wave = tid >> 6, lane = tid & 63;
  int lane15 = lane & 15, quad = lane >> 4;
  int wm = (wave >> 1) * 32, wn = (wave & 1) * 32;
  int bm0 = blockIdx.y * 128, bn0 = blockIdx.x * 64;
  f32x4 acc[2][2] = {};

#define G2_STAGE(bb, kb)                                                       \
  {                                                                            \
    const half_t* Ag = A + (size_t)bm0 * 1024 + (kb);                          \
    const half_t* Bg = Bt + (size_t)bn0 * 1024 + (kb);                         \
    _Pragma("unroll")                                                          \
    for (int p = 0; p < 2; p++) {                                              \
      int fc = (wave * 2 + p) * 64 + lane;                                     \
      int r = fc >> 3, c = (fc & 7) ^ (r & 7);                                 \
      load_lds16(Ag + (size_t)r * 1024 + c * 8, &As[bb][0] + fc * 8);          \
    }                                                                          \
    {                                                                          \
      int fc = wave * 64 + lane;                                               \
      int r = fc >> 3, c = (fc & 7) ^ (r & 7);                                 \
      load_lds16(Bg + (size_t)r * 1024 + c * 8, &Bs[bb][0] + fc * 8);          \
    }                                                                          \
  }

  G2_STAGE(0, 0);
  for (int kt = 0; kt < 16; kt++) {
    __syncthreads();                       // buf[kt&1] DMA drained & visible
    if (kt < 15) G2_STAGE((kt + 1) & 1, (kt + 1) * 64);
    const half_t* Asb = &As[kt & 1][0];
    const half_t* Bsb = &Bs[kt & 1][0];
    #pragma unroll
    for (int ks = 0; ks < 2; ks++) {
      half8 af[2], bf[2];
      #pragma unroll
      for (int i = 0; i < 2; i++) {
        int Ra = wm + i * 16 + lane15;
        af[i] = *(const half8*)(Asb + Ra * 64 + ((ks * 4 + quad) ^ (Ra & 7)) * 8);
      }
      #pragma unroll
      for (int i = 0; i < 2; i++) {
        int Rb = wn + i * 16 + lane15;
        bf[i] = *(const half8*)(Bsb + Rb * 64 + ((ks * 4 + quad) ^ (Rb & 7)) * 8);
      }
      #pragma unroll
      for (int mi = 0; mi < 2; mi++)
        #pragma unroll
        for (int ni = 0; ni < 2; ni++)
          acc[mi][ni] = __builtin_amdgcn_mfma_f32_16x16x32_f16(af[mi], bf[ni], acc[mi][ni], 0, 0, 0);
    }
  }
#undef G2_STAGE
  #pragma unroll
  for (int mi = 0; mi < 2; mi++)
    #pragma unroll
    for (int ni = 0; ni < 2; ni++) {
      int n = bn0 + wn + ni * 16 + lane15;
      float bv = bias[n];
      int mrow = bm0 + wm + mi * 16 + quad * 4;
      #pragma unroll
      for (int r = 0; r < 4; r++)
        C[(size_t)(mrow + r) * 1024 + n] = acc[mi][ni][r] + bv;
    }
}

// ------------- fused QKV GEMM + bias + RoPE + reorg (512 thr + XCD rows) ------
// R13: XCD row-colocation. FETCH was 43MB vs ~15MB unique input: same-row
// blocks (sharing a 256KB A-panel) were scattered across the 8 XCD L2s.
// Remap f=x+24y -> yl=(f&7)+8*(f/192), xl=(f>>3)%24 (bijective): each XCD
// (f%8) owns 4 complete M-rows -> A-panels fetched once per XCD.
__global__ __launch_bounds__(512, 4) void k_gemm_qkv(const half_t* __restrict__ A,
                                                     const half_t* __restrict__ Bt,
                                                     const float* __restrict__ bias,
                                                     const float2* __restrict__ tbl,
                                                     half_t* __restrict__ Qo,
                                                     half_t* __restrict__ Ko,
                                                     half_t* __restrict__ Vo) {
  __shared__ half_t smem[2][16384];        // per buf: As 8192h | Bs 8192h (64KB)
  int tid = threadIdx.x;
  int wave = tid >> 6, lane = tid & 63;
  int lane15 = lane & 15, quad = lane >> 4;
  int wm = (wave >> 1) * 32, wn = (wave & 1) * 64;   // 4M x 2N wave grid
  int f = (int)blockIdx.x + 24 * (int)blockIdx.y;    // gridDim.x == 24
  int xl = (f >> 3) % 24, yl = (f & 7) + 8 * (f / 192);
  int bm0 = yl * 128, bn0 = xl * 128;
  f32x4 acc[2][4] = {};                    // [mi][ni]: 32 AGPR

#define QKV_STAGE(bb, kb)                                                      \
  {                                                                            \
    const half_t* Ag = A + (size_t)bm0 * C_DIM + (kb);                         \
    const half_t* Bg = Bt + (size_t)bn0 * C_DIM + (kb);                        \
    _Pragma("unroll")                                                          \
    for (int p = 0; p < 2; p++) {                                              \
      int fc = (wave * 2 + p) * 64 + lane;                                     \
      int r = fc >> 3, c = (fc & 7) ^ (r & 7);                                 \
      load_lds16(Ag + (size_t)r * C_DIM + c * 8,                               \
                 &smem[bb][0] + (wave * 2 + p) * 512);                         \
      load_lds16(Bg + (size_t)r * C_DIM + c * 8,                               \
                 &smem[bb][8192] + (wave * 2 + p) * 512);                      \
    }                                                                          \
  }

  QKV_STAGE(0, 0);
  for (int kt = 0; kt < 16; kt++) {
    __syncthreads();                       // buf[kt&1] DMA drained & visible
    if (kt < 15) QKV_STAGE((kt + 1) & 1, (kt + 1) * 64);
    const half_t* As = &smem[kt & 1][0];
    const half_t* Bs = &smem[kt & 1][8192];
    #pragma unroll
    for (int ks = 0; ks < 2; ks++) {
      half8 af[2], bf[4];
      #pragma unroll
      for (int i = 0; i < 2; i++) {
        int Ra = wm + i * 16 + lane15;
        af[i] = *(const half8*)(As + Ra * 64 + ((ks * 4 + quad) ^ (Ra & 7)) * 8);
      }
      #pragma unroll
      for (int i = 0; i < 4; i++) {
        int Rb = wn + i * 16 + lane15;
        bf[i] = *(const half8*)(Bs + Rb * 64 + ((ks * 4 + quad) ^ (Rb & 7)) * 8);
      }
      #pragma unroll
      for (int mi = 0; mi < 2; mi++)
        #pragma unroll
        for (int ni = 0; ni < 4; ni++)
          acc[mi][ni] = __builtin_amdgcn_mfma_f32_16x16x32_f16(af[mi], bf[ni], acc[mi][ni], 0, 0, 0);
    }
  }
#undef QKV_STAGE
  // bias (b_attn) BEFORE rope, matching reference
  #pragma unroll
  for (int ni = 0; ni < 4; ni++) {
    float bv = bias[bn0 + wn + ni * 16 + lane15];
    #pragma unroll
    for (int mi = 0; mi < 2; mi++)
      #pragma unroll
      for (int r = 0; r < 4; r++) acc[mi][ni][r] += bv;
  }

  int third = bn0 >> 10;                   // 0=Q, 1=K, 2=V (block-uniform)
  if (third < 2) {
    half_t* Ob = (third == 0) ? Qo : Ko;
    int h = ((bn0 & 1023) + wn) >> 6;      // one head per wave (wn in {0,64})
    #pragma unroll
    for (int mi = 0; mi < 2; mi++) {
      int mrow = bm0 + wm + mi * 16 + quad * 4;
      int bq = mrow >> 11, tq = mrow & 2047;
      half_t* outp = Ob + ((size_t)(bq * 16 + h) * T_SEQ + tq) * HD;
      #pragma unroll
      for (int p = 0; p < 2; p++) {        // pair (d=j, d=j+32), j = p*16+lane15
        int j = p * 16 + lane15;
        #pragma unroll
        for (int r = 0; r < 4; r++) {
          float2 cs = tbl[(tq + r) * 32 + j];
          float a1 = acc[mi][p][r], a2 = acc[mi][p + 2][r];
          float o1 = a1 * cs.x - a2 * cs.y;
          float o2 = a1 * cs.y + a2 * cs.x;
          if (third == 0) { o1 *= QSCALE; o2 *= QSCALE; }
          outp[r * HD + j]      = (half_t)o1;
          outp[r * HD + j + 32] = (half_t)o2;
        }
      }
    }
  } else {
    // V: transpose through LDS, store blocked [bh][t/64][d][t%64]
    __syncthreads();                       // all waves done reading smem
    half_t* vt = &smem[0][0];              // [128][130], 33280B < 64KB
    #pragma unroll
    for (int mi = 0; mi < 2; mi++)
      #pragma unroll
      for (int ni = 0; ni < 4; ni++) {
        int tl = wm + mi * 16 + quad * 4, nl = wn + ni * 16 + lane15;
        #pragma unroll
        for (int r = 0; r < 4; r++)
          vt[(tl + r) * 130 + nl] = (half_t)acc[mi][ni][r];
      }
    __syncthreads();
    int hV = (bn0 - 2048) >> 6;
    int bq = bm0 >> 11, tq0 = bm0 & 2047;
    int c8 = (tid & 7) * 8;                // 8 lanes cover one 64-t row chunk
    #pragma unroll
    for (int p = 0; p < 4; p++) {
      int gr = p * 64 + (tid >> 3);        // 256 rows: (h2, d, tblk)
      int tb = gr & 1, d = (gr >> 1) & 63, h2 = gr >> 7;
      half8 vv;
      #pragma unroll
      for (int jj = 0; jj < 8; jj++)
        vv[jj] = vt[(tb * 64 + c8 + jj) * 130 + h2 * 64 + d];
      *(half8*)(Vo + ((size_t)((bq * 16 + hV + h2) * 32 + (tq0 >> 6) + tb) * 64 + d) * 64 + c8) = vv;
    }
  }
}

// ------------- causal flash v5 (R11 known-good, reverted from v6) -------------
// R12 lesson: l-via-MFMA added 2 f32x4 live accs at zero register headroom ->
// scratch spills (WRITE 8->34.8MB) -> 45->69us. Reverted verbatim to R11.
template <bool DIAG>
__device__ __forceinline__ void tile_mfma(const half_t* __restrict__ Kt,
                                          const half_t* __restrict__ Vt,
                                          half8 bq0, half8 bq1,
                                          f32x4 (&ot)[4], float& l,
                                          int lane15, int quad, int qloc) {
  f32x4 sacc[4];
  #pragma unroll
  for (int s = 0; s < 4; s++) {
    int R_ = s * 16 + lane15;
    half8 ak0 = *(const half8*)(Kt + R_ * 64 + ((quad) ^ (R_ & 7)) * 8);
    half8 ak1 = *(const half8*)(Kt + R_ * 64 + ((4 + quad) ^ (R_ & 7)) * 8);
    f32x4 z = {};
    z = __builtin_amdgcn_mfma_f32_16x16x32_f16(ak0, bq0, z, 0, 0, 0);
    sacc[s] = __builtin_amdgcn_mfma_f32_16x16x32_f16(ak1, bq1, z, 0, 0, 0);
  }
  #pragma unroll
  for (int s = 0; s < 4; s++) {
    half4 bp;
    #pragma unroll
    for (int r = 0; r < 4; r++) {
      float sv = sacc[s][r];
      if (DIAG && (s * 16 + quad * 4 + r > qloc)) sv = -1.0e30f;
      float p = exp2f(fminf(sv, 14.0f));
      l += p;
      bp[r] = (half_t)p;
    }
    #pragma unroll
    for (int nm = 0; nm < 4; nm++) {
      int Rv = nm * 16 + lane15;
      half4 av = *(const half4*)(Vt + Rv * 64 +
                                 ((2 * s + (quad >> 1)) ^ (Rv & 7)) * 8 +
                                 (quad & 1) * 4);
      ot[nm] = __builtin_amdgcn_mfma_f32_16x16x16f16(av, bp, ot[nm], 0, 0, 0);
    }
  }
}

// Stage super-round s_: kv tiles {4s, 4s+1} (sub 0) and {4s+2, 4s+3} (sub 1)
// of K and V into buffer bb. 1024 threads x 4 load_lds16 (16B) = 64KB.
#define STAGE2(bb, s_)                                                         \
  {                                                                            \
    int gS = wave >> 3;                                                        \
    int idx = (wave & 7) * 64 + lane;                                          \
    int rr_ = idx >> 3, cc = (idx & 7) ^ (rr_ & 7);                            \
    _Pragma("unroll")                                                          \
    for (int sub = 0; sub < 2; sub++) {                                        \
      int j = 4 * (s_) + 2 * sub + gS;                                         \
      load_lds16(Kb + (size_t)(j * 64 + rr_) * HD + cc * 8,                    \
                 &KV[bb][sub][0][gS][0] + idx * 8);                            \
      load_lds16(Vb + (size_t)j * 4096 + rr_ * 64 + cc * 8,                    \
                 &KV[bb][sub][1][gS][0] + idx * 8);                            \
    }                                                                          \
  }

__global__ __launch_bounds__(1024, 4) void k_flash(const half_t* __restrict__ Qg,
                                                   const half_t* __restrict__ Kg,
                                                   const half_t* __restrict__ Vg,
                                                   half_t* __restrict__ y) {
  __shared__ half_t KV[2][2][2][2][4096];  // [buf][sub][K/V][parity][64*64] 128KB
  // XCD-colocation swizzle (XCD = flat % 8): all 8 blocks of one bh share an
  // XCD -> K/V L2-resident (verified R8: FETCH 71.5 -> 12.4MB).
  int flat = (int)blockIdx.x + 8 * (int)blockIdx.y;
  int x  = (flat >> 3) & 7;                // q-tile pair id 0..7
  int bh = (flat & 7) | ((flat >> 6) << 3);
  int b = bh >> 4, h = bh & 15;
  int tid = threadIdx.x;
  int wave = tid >> 6, lane = tid & 63;
  int g = wave >> 3, wq = wave & 7;        // kv-parity group, q-warp in group
  int lane15 = lane & 15, quad = lane >> 4;
  const half_t* Qb = Qg + (size_t)bh * T_SEQ * HD;
  const half_t* Kb = Kg + (size_t)bh * T_SEQ * HD;
  const half_t* Vb = Vg + (size_t)bh * HD * T_SEQ;

  int qtA = x, qtB = 15 - x;               // A < B always
  int jA = 2 * qtA, jB = 2 * qtB;          // diagonal kv-tile bases
  int qlA = qtA * 128 + wq * 16 + lane15;
  int qlB = qtB * 128 + wq * 16 + lane15;
  half8 aq0 = *(const half8*)(Qb + (size_t)qlA * HD + quad * 8);
  half8 aq1 = *(const half8*)(Qb + (size_t)qlA * HD + 32 + quad * 8);
  half8 bq0 = *(const half8*)(Qb + (size_t)qlB * HD + quad * 8);
  half8 bq1 = *(const half8*)(Qb + (size_t)qlB * HD + 32 + quad * 8);
  f32x4 otA[4] = {}, otB[4] = {};
  float lA = 0.f, lB = 0.f;

  int R = 16 - x;                          // rounds; tiles consumed 2/round
  int S = (R + 1) >> 1;                    // super-rounds (4 tiles per stage)
  STAGE2(0, 0);
  for (int s = 0; s < S; s++) {
    __syncthreads();                       // stage(s) DMA drained & visible
    if (s + 1 < S) STAGE2((s + 1) & 1, s + 1);  // prefetch overlaps compute
    #pragma unroll
    for (int sub = 0; sub < 2; sub++) {
      const half_t* Kt = &KV[s & 1][sub][0][g][0];
      const half_t* Vt = &KV[s & 1][sub][1][g][0];
      int j = 2 * (2 * s + sub) + g;       // this group's kv tile
      // tile A (q rows 128x..128x+127): active while j <= jA+1
      if (j < jA)
        tile_mfma<false>(Kt, Vt, aq0, aq1, otA, lA, lane15, quad, 0);
      else if (j == jA)                    // parity 0 -> group 0 only
        tile_mfma<true>(Kt, Vt, aq0, aq1, otA, lA, lane15, quad,
                        wq * 16 + lane15);
      else if (j == jA + 1 && wq >= 4)     // parity 1 -> group 1; wq<4 masked
        tile_mfma<true>(Kt, Vt, aq0, aq1, otA, lA, lane15, quad,
                        (wq - 4) * 16 + lane15);
      // tile B (q rows 128(15-x)..): active while j <= jB+1
      if (j < jB)
        tile_mfma<false>(Kt, Vt, bq0, bq1, otB, lB, lane15, quad, 0);
      else if (j == jB)
        tile_mfma<true>(Kt, Vt, bq0, bq1, otB, lB, lane15, quad,
                        wq * 16 + lane15);
      else if (j == jB + 1 && wq >= 4)
        tile_mfma<true>(Kt, Vt, bq0, bq1, otB, lB, lane15, quad,
                        (wq - 4) * 16 + lane15);
    }
  }
  // per-wave l: sum the 4 quads holding each q-column
  lA += __shfl_xor(lA, 16); lA += __shfl_xor(lA, 32);
  lB += __shfl_xor(lB, 16); lB += __shfl_xor(lB, 32);
  // cross-group combine via LDS (reuse KV region, 512*17*4B = 34.8KB <= 128KB)
  float* cb = (float*)&KV[0][0][0][0][0];
  int ci = (wq * 64 + lane) * 17;          // stride 17 floats: conflict-free
  // ---- tile A ----
  __syncthreads();                         // all K/V reads done; region free
  if (g == 1) {
    #pragma unroll
    for (int nm = 0; nm < 4; nm++)
      #pragma unroll
      for (int r = 0; r < 4; r++) cb[ci + nm * 4 + r] = otA[nm][r];
    cb[ci + 16] = lA;
  }
  __syncthreads();
  if (g == 0) {
    #pragma unroll
    for (int nm = 0; nm < 4; nm++)
      #pragma unroll
      for (int r = 0; r < 4; r++) otA[nm][r] += cb[ci + nm * 4 + r];
    lA += cb[ci + 16];
    float invl = 1.0f / lA;
    int t = qtA * 128 + wq * 16 + lane15;
    half_t* yr = y + (size_t)(b * T_SEQ + t) * C_DIM + h * 64;
    #pragma unroll
    for (int nm = 0; nm < 4; nm++) {
      half4 o4;
      #pragma unroll
      for (int r = 0; r < 4; r++) o4[r] = (half_t)(otA[nm][r] * invl);
      *(half4*)(yr + nm * 16 + quad * 4) = o4;   // 8B store
    }
  }
  // ---- tile B ----
  __syncthreads();
  if (g == 1) {
    #pragma unroll
    for (int nm = 0; nm < 4; nm++)
      #pragma unroll
      for (int r = 0; r < 4; r++) cb[ci + nm * 4 + r] = otB[nm][r];
    cb[ci + 16] = lB;
  }
  __syncthreads();
  if (g == 0) {
    #pragma unroll
    for (int nm = 0; nm < 4; nm++)
      #pragma unroll
      for (int r = 0; r < 4; r++) otB[nm][r] += cb[ci + nm * 4 + r];
    lB += cb[ci + 16];
    float invl = 1.0f / lB;
    int t = qtB * 128 + wq * 16 + lane15;
    half_t* yr = y + (size_t)(b * T_SEQ + t) * C_DIM + h * 64;
    #pragma unroll
    for (int nm = 0; nm < 4; nm++) {
      half4 o4;
      #pragma unroll
      for (int r = 0; r < 4; r++) o4[r] = (half_t)(otB[nm][r] * invl);
      *(half4*)(yr + nm * 16 + quad * 4) = o4;   // 8B store
    }
  }
  #undef STAGE2
}

extern "C" void kernel_launch(void* const* d_in, const int* in_sizes, int n_in,
                              void* d_out, int out_size, void* d_ws, size_t ws_size,
                              hipStream_t stream) {
  const float* x      = (const float*)d_in[0];
  const float* w_attn = (const float*)d_in[1];
  const float* b_attn = (const float*)d_in[2];
  const float* w_proj = (const float*)d_in[3];
  const float* b_proj = (const float*)d_in[4];
  float* out = (float*)d_out;

  char* ws = (char*)d_ws;
  const size_t MB = 1u << 20;
  half_t* xb  = (half_t*)(ws);             // 8 MB  x in f16
  half_t* wT  = (half_t*)(ws + 8 * MB);    // 6 MB  w_attn^T f16 [3072][1024]
  half_t* wpT = (half_t*)(ws + 14 * MB);   // 2 MB  w_proj^T f16 [1024][1024]
  half_t* Q   = (half_t*)(ws + 16 * MB);   // 8 MB  [bh][t][d]  (pre-scaled)
  half_t* Kb  = (half_t*)(ws + 24 * MB);   // 8 MB  [bh][t][d]
  half_t* Vt  = (half_t*)(ws + 32 * MB);   // 8 MB  [bh][t/64][d][t%64] blocked
  half_t* y   = (half_t*)(ws + 40 * MB);   // 8 MB  attn out f16
  float2* tbl = (float2*)(ws + 48 * MB);   // 512KB rope table [2048][32]

  k_prep<<<4096 + 768 + 256 + 256, 256, 0, stream>>>(x, xb, w_attn, wT,
                                                     w_proj, wpT, tbl);
  k_gemm_qkv<<<dim3(N_QKV / 128, M_ROWS / 128), 512, 0, stream>>>(
      xb, wT, b_attn, tbl, Q, Kb, Vt);
  k_flash<<<dim3(8, B_SZ * N_HEADS), 1024, 0, stream>>>(Q, Kb, Vt, y);
  k_gemm2<<<dim3(C_DIM / 64, M_ROWS / 128), 512, 0, stream>>>(
      y, wpT, b_proj, out);
}